// Round 6
// baseline (276.815 us; speedup 1.0000x reference)
//
#include <hip/hip_runtime.h>
#include <hip/hip_bf16.h>
#include <stdint.h>

// Workspace layout (bytes):
//  outbf  [0,        33554432)   out cast to bf16        (B*T*D)
//  vbf    [33554432, 67108864)   V = out @ W_write^T, bf16
//  wwbf   [67108864, 69206016)   W_write bf16
//  wrbf   [69206016, 71303168)   W_read  bf16
//  intra  [71303168, 104857600)  intra reads bf16 (flat B,T,D layout)
//  U      [104857600,138412032)  per-chunk outer products bf16 [BH][64][64*64]
//  Wst    [138412032,171966464)  pre-chunk W states bf16 [BH][64][64*64]
//  reads  [171966464,205520896)  alpha*(inter+intra) bf16 (flat B,T,D)

typedef __bf16 bf16x8 __attribute__((ext_vector_type(8)));
typedef float f32x4 __attribute__((ext_vector_type(4)));

#define GAS __attribute__((address_space(1)))
#define LAS __attribute__((address_space(3)))

__device__ __forceinline__ unsigned short f2bf(float f) {
  unsigned u = __float_as_uint(f);
  u = (u + 0x7fffu + ((u >> 16) & 1u)) >> 16;   // RNE
  return (unsigned short)u;
}
__device__ __forceinline__ float bf2f(unsigned short h) {
  return __uint_as_float(((unsigned)h) << 16);
}

// ---------------------------------------------------------------- fused cast f32->bf16
__global__ __launch_bounds__(256) void cast_all(
    const float* __restrict__ outf, const float* __restrict__ w1,
    const float* __restrict__ w2, unsigned short* __restrict__ outbf,
    unsigned short* __restrict__ wbf) {
  int i = blockIdx.x * 256 + threadIdx.x;
  const float* src;
  uint4* dst;
  int j;
  if (i < 2097152) {
    src = outf; j = i; dst = (uint4*)outbf;
  } else {
    j = i - 2097152;
    dst = (uint4*)wbf;
    if (j < 131072) { src = w1; }
    else { src = w2; j -= 131072; dst += 131072; }
  }
  const float4* s = (const float4*)src + (size_t)j * 2;
  float4 f0 = s[0], f1 = s[1];
  union { uint4 u4; unsigned short us[8]; } o;
  o.us[0] = f2bf(f0.x); o.us[1] = f2bf(f0.y); o.us[2] = f2bf(f0.z); o.us[3] = f2bf(f0.w);
  o.us[4] = f2bf(f1.x); o.us[5] = f2bf(f1.y); o.us[6] = f2bf(f1.z); o.us[7] = f2bf(f1.w);
  dst[(i < 2097152) ? i : (i - 2097152 < 131072 ? i - 2097152 : i - 2097152 - 131072)] = o.u4;
}

// ---------------------------------------------------------------- 256x256 8-phase GEMM
// Frozen (R5): chunk-uniform XOR swizzle, bank-conflict-free (measured 0).
#define STG(XB, SLOT, HIDX, HF, KT)                                                  \
  do {                                                                               \
    if ((KT) < nT) {                                                                 \
      _Pragma("unroll") for (int r_ = 0; r_ < 2; r_++)                               \
          __builtin_amdgcn_global_load_lds(                                          \
              (GAS void*)(void*)((XB) +                                              \
                                 (size_t)((HF) * 128 + (tid >> 3) + r_ * 64) * K +   \
                                 ((KT) << 6) + srcc),                                \
              (LAS void*)(&lds[SLOT][HIDX][w64 * 512 + r_ * 4096]), 16, 0, 0);       \
    }                                                                                \
  } while (0)

#define DSRA(SLOT, MH)                                                               \
  _Pragma("unroll") for (int m_ = 0; m_ < 4; m_++)                                   \
  _Pragma("unroll") for (int ks_ = 0; ks_ < 2; ks_++)                                \
      a[m_][ks_] = *(const bf16x8*)&lds[SLOT][aH][((MH) * 64 + m_ * 16 + lm) * 64 +  \
                                                  (((ks_ * 4 + q4) ^ lsw) * 8)];

#define DSRB(SLOT, BB, N0)                                                           \
  _Pragma("unroll") for (int n_ = 0; n_ < 2; n_++)                                   \
  _Pragma("unroll") for (int ks_ = 0; ks_ < 2; ks_++)                                \
      BB[n_][ks_] = *(const bf16x8*)&lds[SLOT][bH][(brow0 + ((N0) + n_) * 16 + lm) * 64 + \
                                                   (((ks_ * 4 + q4) ^ lsw) * 8)];

#define MMA(MH, BB, N0)                                                              \
  __builtin_amdgcn_s_setprio(1);                                                     \
  _Pragma("unroll") for (int m_ = 0; m_ < 4; m_++)                                   \
  _Pragma("unroll") for (int n_ = 0; n_ < 2; n_++)                                   \
  _Pragma("unroll") for (int ks_ = 0; ks_ < 2; ks_++)                                \
      acc[(MH) * 4 + m_][(N0) + n_] = __builtin_amdgcn_mfma_f32_16x16x32_bf16(       \
          a[m_][ks_], BB[n_][ks_], acc[(MH) * 4 + m_][(N0) + n_], 0, 0, 0);          \
  __builtin_amdgcn_s_setprio(0);

#define BARW                                                                         \
  __builtin_amdgcn_s_barrier();                                                      \
  asm volatile("s_waitcnt lgkmcnt(0)" ::: "memory");                                 \
  __builtin_amdgcn_sched_barrier(0);

#define BARE                                                                         \
  __builtin_amdgcn_s_barrier();                                                      \
  __builtin_amdgcn_sched_barrier(0);

template <bool ADD>
__global__ __launch_bounds__(512, 2) void gemm256(
    const unsigned short* __restrict__ A, const unsigned short* __restrict__ B,
    const unsigned short* __restrict__ base_bf, void* __restrict__ Cout,
    int M, int N, int K) {
  __shared__ unsigned short lds[2][4][8192];
  int tid = threadIdx.x;
  int l = tid & 63, w64 = tid >> 6;
  int lm = l & 15, q4 = l >> 4;
  int lsw = lm & 7;
  int srcc = (((tid & 7) ^ ((tid >> 3) & 7)) * 8);
  int aH = w64 >> 2;
  int bH = 2 + ((w64 & 3) >> 1);
  int brow0 = (w64 & 1) * 64;
  int id = blockIdx.x;
  int xcd = id & 7, s = id >> 3;
  int bn = s & 3, bm = (s >> 2) * 8 + xcd;
  const unsigned short* Ab = A + (size_t)bm * 256 * K;
  const unsigned short* Bb = B + (size_t)bn * 256 * K;
  const int nT = K >> 6, nI = nT >> 1;

  STG(Bb, 0, 2, 0, 0); STG(Bb, 0, 3, 1, 0);
  STG(Ab, 0, 0, 0, 0); STG(Ab, 0, 1, 1, 0);
  STG(Bb, 1, 2, 0, 1); STG(Bb, 1, 3, 1, 1);
  asm volatile("s_waitcnt vmcnt(4)" ::: "memory");
  __builtin_amdgcn_s_barrier();
  __builtin_amdgcn_sched_barrier(0);

  f32x4 acc[8][4];
  if constexpr (ADD) {
#pragma unroll
    for (int mh = 0; mh < 2; mh++)
#pragma unroll
      for (int m = 0; m < 4; m++)
#pragma unroll
        for (int nf = 0; nf < 4; nf++) {
          int r0 = bm * 256 + (w64 >> 2) * 128 + mh * 64 + m * 16 + q4 * 4;
          int col = bn * 256 + (w64 & 3) * 64 + nf * 16 + lm;
#pragma unroll
          for (int j = 0; j < 4; j++)
            acc[mh * 4 + m][nf][j] = bf2f(base_bf[(size_t)(r0 + j) * N + col]);
        }
  } else {
#pragma unroll
    for (int mf = 0; mf < 8; mf++)
#pragma unroll
      for (int nf = 0; nf < 4; nf++) acc[mf][nf] = (f32x4){0.f, 0.f, 0.f, 0.f};
  }

  bf16x8 a[4][2], b0[2][2], b1[2][2];
  for (int i = 0; i < nI; i++) {
    int t1 = 2 * i + 1, t2 = 2 * i + 2, t3 = 2 * i + 3;
    DSRA(0, 0); DSRB(0, b0, 0); STG(Ab, 1, 0, 0, t1);   // P1
    BARW; MMA(0, b0, 0); BARE;
    DSRB(0, b1, 2); STG(Ab, 1, 1, 1, t1);               // P2
    BARW; MMA(0, b1, 2); BARE;
    DSRA(0, 1); STG(Bb, 0, 2, 0, t2);                   // P3
    BARW; MMA(1, b1, 2); BARE;
    STG(Bb, 0, 3, 1, t2);                               // P4
    BARW; MMA(1, b0, 0);
    if (i < nI - 1) { asm volatile("s_waitcnt vmcnt(4)" ::: "memory"); }
    else            { asm volatile("s_waitcnt vmcnt(0)" ::: "memory"); }
    BARE;
    DSRA(1, 0); DSRB(1, b0, 0); STG(Ab, 0, 0, 0, t2);   // P5
    BARW; MMA(0, b0, 0); BARE;
    DSRB(1, b1, 2); STG(Ab, 0, 1, 1, t2);               // P6
    BARW; MMA(0, b1, 2); BARE;
    DSRA(1, 1); STG(Bb, 1, 2, 0, t3);                   // P7
    BARW; MMA(1, b1, 2); BARE;
    STG(Bb, 1, 3, 1, t3);                               // P8
    BARW; MMA(1, b0, 0);
    if (i < nI - 1) { asm volatile("s_waitcnt vmcnt(4)" ::: "memory"); }
    BARE;
  }

#pragma unroll
  for (int mh = 0; mh < 2; mh++)
#pragma unroll
    for (int m = 0; m < 4; m++)
#pragma unroll
      for (int nf = 0; nf < 4; nf++) {
        int r0 = bm * 256 + (w64 >> 2) * 128 + mh * 64 + m * 16 + q4 * 4;
        int col = bn * 256 + (w64 & 3) * 64 + nf * 16 + lm;
#pragma unroll
        for (int j = 0; j < 4; j++) {
          if constexpr (ADD)
            ((float*)Cout)[(size_t)(r0 + j) * N + col] = acc[mh * 4 + m][nf][j];
          else
            ((unsigned short*)Cout)[(size_t)(r0 + j) * N + col] = f2bf(acc[mh * 4 + m][nf][j]);
        }
      }
}

// ---------------------------------------------------------------- per-chunk local work
// R6: intra and U stores routed through LDS (bounce) -> coalesced 16B/lane global
// stores instead of 32 scalar 2B scatters per thread. Values bit-identical.
__global__ __launch_bounds__(256) void chunk_local(
    const unsigned short* __restrict__ rkg,   // outbf flat [B*T*D]
    const unsigned short* __restrict__ vg,    // vbf flat
    const float* __restrict__ decay,
    unsigned short* __restrict__ intra_bf,    // flat [B*T*D]
    unsigned short* __restrict__ U_bf) {      // [BH][64][64*64]
  int c = blockIdx.x, bh = blockIdx.y;
  int b = bh >> 4, h = bh & 15;
  int tid = threadIdx.x, l = tid & 63, w = tid >> 6;
  float gamma = 1.0f / (1.0f + __expf(-decay[h]));
  float lg = __logf(gamma);

  __shared__ unsigned short kr_s[65 * 72];   // kr_s[p] = token c*64-1+p (p=0..64)
  __shared__ unsigned short wkT_s[64 * 72];  // transpose of kr_s rows 0..63
  __shared__ unsigned short vT_s[64 * 72];
  __shared__ unsigned short S_s[64 * 72];
  __shared__ float pw_s[64];                 // gamma^d

  if (tid < 64) pw_s[tid] = __expf(lg * (float)tid);

  const size_t rowbase = (((size_t)b * 4096 + (size_t)c * 64) * 1024) + h * 64;
  const size_t bb = (size_t)b * 4096;

#pragma unroll
  for (int r = 0; r < 2; r++) {
    int e = r * 256 + tid;
    int p = e >> 3, seg = e & 7;
    uint4 dv = *(const uint4*)(vg + rowbase + (size_t)p * 1024 + seg * 8);
    {
      unsigned uu[4] = {dv.x, dv.y, dv.z, dv.w};
#pragma unroll
      for (int qq = 0; qq < 4; qq++) {
        vT_s[(seg * 8 + qq * 2) * 72 + p] = (unsigned short)(uu[qq] & 0xffffu);
        vT_s[(seg * 8 + qq * 2 + 1) * 72 + p] = (unsigned short)(uu[qq] >> 16);
      }
    }
    int tg = c * 64 - 1 + p;
    uint4 dw = make_uint4(0u, 0u, 0u, 0u);
    if (tg >= 0) dw = *(const uint4*)(rkg + (bb + tg) * 1024 + h * 64 + seg * 8);
    *(uint4*)&kr_s[p * 72 + seg * 8] = dw;
    {
      unsigned uu[4] = {dw.x, dw.y, dw.z, dw.w};
#pragma unroll
      for (int qq = 0; qq < 4; qq++) {
        wkT_s[(seg * 8 + qq * 2) * 72 + p] = (unsigned short)(uu[qq] & 0xffffu);
        wkT_s[(seg * 8 + qq * 2 + 1) * 72 + p] = (unsigned short)(uu[qq] >> 16);
      }
    }
  }
  if (tid < 8) {
    uint4 dw = *(const uint4*)(rkg + (bb + (size_t)c * 64 + 63) * 1024 + h * 64 + tid * 8);
    *(uint4*)&kr_s[64 * 72 + tid * 8] = dw;
  }
  __syncthreads();

  int lm = l & 15, q4 = l >> 4;

  // Phase 1: S = rk @ wk^T, mask, bf16
  {
    bf16x8 a0 = *(const bf16x8*)&kr_s[(w * 16 + lm + 1) * 72 + q4 * 8];
    bf16x8 a1 = *(const bf16x8*)&kr_s[(w * 16 + lm + 1) * 72 + 32 + q4 * 8];
#pragma unroll
    for (int ni = 0; ni < 4; ni++) {
      bf16x8 b0 = *(const bf16x8*)&kr_s[(ni * 16 + lm) * 72 + q4 * 8];
      bf16x8 b1 = *(const bf16x8*)&kr_s[(ni * 16 + lm) * 72 + 32 + q4 * 8];
      f32x4 acc = {0.f, 0.f, 0.f, 0.f};
      acc = __builtin_amdgcn_mfma_f32_16x16x32_bf16(a0, b0, acc, 0, 0, 0);
      acc = __builtin_amdgcn_mfma_f32_16x16x32_bf16(a1, b1, acc, 0, 0, 0);
#pragma unroll
      for (int j = 0; j < 4; j++) {
        int p = w * 16 + q4 * 4 + j;
        int q = ni * 16 + lm;
        float m = (p > q) ? pw_s[p - 1 - q] : 0.0f;
        S_s[p * 72 + q] = f2bf(acc[j] * m);
      }
    }
  }
  __syncthreads();

  // Phase 2: intra = (S.M) @ v  -> bounce result through S_s, coalesced store
  {
    bf16x8 a0 = *(const bf16x8*)&S_s[(w * 16 + lm) * 72 + q4 * 8];
    bf16x8 a1 = *(const bf16x8*)&S_s[(w * 16 + lm) * 72 + 32 + q4 * 8];
    f32x4 accs[4];
#pragma unroll
    for (int ni = 0; ni < 4; ni++) {
      bf16x8 b0 = *(const bf16x8*)&vT_s[(ni * 16 + lm) * 72 + q4 * 8];
      bf16x8 b1 = *(const bf16x8*)&vT_s[(ni * 16 + lm) * 72 + 32 + q4 * 8];
      f32x4 acc = {0.f, 0.f, 0.f, 0.f};
      acc = __builtin_amdgcn_mfma_f32_16x16x32_bf16(a0, b0, acc, 0, 0, 0);
      accs[ni] = __builtin_amdgcn_mfma_f32_16x16x32_bf16(a1, b1, acc, 0, 0, 0);
    }
    __syncthreads();   // all S_s fragment reads complete
#pragma unroll
    for (int ni = 0; ni < 4; ni++)
#pragma unroll
      for (int j = 0; j < 4; j++) {
        int p = w * 16 + q4 * 4 + j;
        int i = ni * 16 + lm;
        S_s[p * 72 + i] = f2bf(accs[ni][j]);
      }
    __syncthreads();
#pragma unroll
    for (int r = 0; r < 2; r++) {
      int e = r * 256 + tid;
      int p = e >> 3, seg = e & 7;
      *(uint4*)(intra_bf + rowbase + (size_t)p * 1024 + seg * 8) =
          *(const uint4*)&S_s[p * 72 + seg * 8];
    }
  }

  // Phase 3: U = (v * g_w)^T @ wk  -> bounce result through wkT_s, coalesced store
  {
    bf16x8 a0 = *(const bf16x8*)&vT_s[(w * 16 + lm) * 72 + q4 * 8];
    bf16x8 a1 = *(const bf16x8*)&vT_s[(w * 16 + lm) * 72 + 32 + q4 * 8];
#pragma unroll
    for (int jj = 0; jj < 8; jj++) {
      int p0 = q4 * 8 + jj;
      a0[jj] = (__bf16)((float)a0[jj] * pw_s[63 - p0]);
      a1[jj] = (__bf16)((float)a1[jj] * pw_s[63 - (p0 + 32)]);
    }
    f32x4 accs[4];
#pragma unroll
    for (int nj = 0; nj < 4; nj++) {
      bf16x8 b0 = *(const bf16x8*)&wkT_s[(nj * 16 + lm) * 72 + q4 * 8];
      bf16x8 b1 = *(const bf16x8*)&wkT_s[(nj * 16 + lm) * 72 + 32 + q4 * 8];
      f32x4 acc = {0.f, 0.f, 0.f, 0.f};
      acc = __builtin_amdgcn_mfma_f32_16x16x32_bf16(a0, b0, acc, 0, 0, 0);
      accs[nj] = __builtin_amdgcn_mfma_f32_16x16x32_bf16(a1, b1, acc, 0, 0, 0);
    }
    __syncthreads();   // all wkT_s fragment reads complete
#pragma unroll
    for (int nj = 0; nj < 4; nj++)
#pragma unroll
      for (int j = 0; j < 4; j++) {
        int i = w * 16 + q4 * 4 + j;
        int col = nj * 16 + lm;
        wkT_s[i * 72 + col] = f2bf(accs[nj][j]);
      }
    __syncthreads();
    size_t ub = ((size_t)bh * 64 + c) * 4096;
#pragma unroll
    for (int r = 0; r < 2; r++) {
      int e = r * 256 + tid;
      *(uint4*)(U_bf + ub + (size_t)e * 8) = *(const uint4*)&wkT_s[(e >> 3) * 72 + (e & 7) * 8];
    }
  }
}

// ---------------------------------------------------------------- parallel weighted prefix scan
__global__ __launch_bounds__(256) void scan_w(
    const unsigned short* __restrict__ U_bf, const float* __restrict__ decay,
    unsigned short* __restrict__ Wst) {
  int nsl = blockIdx.x, bh = blockIdx.y;
  int h = bh & 15;
  float gamma = 1.0f / (1.0f + __expf(-decay[h]));
  float gC = __expf(64.0f * __logf(gamma));
  int n0 = nsl * 1024 + threadIdx.x * 4;
  const unsigned short* Ub = U_bf + (size_t)bh * 64 * 4096 + n0;
  unsigned short* Wb = Wst + (size_t)bh * 64 * 4096 + n0;
  float w0 = 0.f, w1 = 0.f, w2 = 0.f, w3 = 0.f;
#pragma unroll
  for (int c = 0; c < 64; c++) {
    uint2 u = *(const uint2*)(Ub + (size_t)c * 4096);
    ushort4 sv;
    sv.x = f2bf(w0); sv.y = f2bf(w1); sv.z = f2bf(w2); sv.w = f2bf(w3);
    *(ushort4*)(Wb + (size_t)c * 4096) = sv;
    w0 = gC * w0 + bf2f((unsigned short)(u.x & 0xffffu));
    w1 = gC * w1 + bf2f((unsigned short)(u.x >> 16));
    w2 = gC * w2 + bf2f((unsigned short)(u.y & 0xffffu));
    w3 = gC * w3 + bf2f((unsigned short)(u.y >> 16));
  }
}

// ---------------------------------------------------------------- inter + combine (parallel)
// R6: gamma^p via LDS table (identical __expf values); combine results written back
// into in_s then stored coalesced 16B/lane (was 16 scalar 2B stores per thread).
__global__ __launch_bounds__(256) void inter_combine(
    const unsigned short* __restrict__ rkg, const unsigned short* __restrict__ Wst,
    const unsigned short* __restrict__ intra_bf,
    const float* __restrict__ decay, const float* __restrict__ log_alpha,
    unsigned short* __restrict__ reads_bf) {
  int c = blockIdx.x, bh = blockIdx.y;
  int b = bh >> 4, h = bh & 15;
  int tid = threadIdx.x, l = tid & 63, w = tid >> 6;
  int lm = l & 15, q4 = l >> 4;
  float gamma = 1.0f / (1.0f + __expf(-decay[h]));
  float lg = __logf(gamma);
  float alpha = __expf(log_alpha[h]);

  __shared__ unsigned short rk_s[64 * 72];
  __shared__ unsigned short W_s[64 * 72];
  __shared__ unsigned short in_s[64 * 72];
  __shared__ float pw_s[64];

  if (tid < 64) pw_s[tid] = __expf(lg * (float)tid);

  const size_t rowbase = (((size_t)b * 4096 + (size_t)c * 64) * 1024) + h * 64;
  const size_t wbase = ((size_t)bh * 64 + c) * 4096;

#pragma unroll
  for (int r = 0; r < 2; r++) {
    int e = r * 256 + tid;
    int p = e >> 3, seg = (e & 7) * 8;
    *(uint4*)&rk_s[p * 72 + seg] = *(const uint4*)(rkg + rowbase + (size_t)p * 1024 + seg);
    *(uint4*)&in_s[p * 72 + seg] = *(const uint4*)(intra_bf + rowbase + (size_t)p * 1024 + seg);
    *(uint4*)&W_s[p * 72 + seg] = *(const uint4*)(Wst + wbase + (size_t)p * 64 + seg);
  }
  __syncthreads();

  bf16x8 a0 = *(const bf16x8*)&rk_s[(w * 16 + lm) * 72 + q4 * 8];
  bf16x8 a1 = *(const bf16x8*)&rk_s[(w * 16 + lm) * 72 + 32 + q4 * 8];
#pragma unroll
  for (int ni = 0; ni < 4; ni++) {
    bf16x8 b0 = *(const bf16x8*)&W_s[(ni * 16 + lm) * 72 + q4 * 8];
    bf16x8 b1 = *(const bf16x8*)&W_s[(ni * 16 + lm) * 72 + 32 + q4 * 8];
    f32x4 acc = {0.f, 0.f, 0.f, 0.f};
    acc = __builtin_amdgcn_mfma_f32_16x16x32_bf16(a0, b0, acc, 0, 0, 0);
    acc = __builtin_amdgcn_mfma_f32_16x16x32_bf16(a1, b1, acc, 0, 0, 0);
#pragma unroll
    for (int j = 0; j < 4; j++) {
      int p = w * 16 + q4 * 4 + j;
      int i = ni * 16 + lm;
      // each (p,i) location is read and written only by this thread after staging
      in_s[p * 72 + i] = f2bf(alpha * (acc[j] * pw_s[p] + bf2f(in_s[p * 72 + i])));
    }
  }
  __syncthreads();
#pragma unroll
  for (int r = 0; r < 2; r++) {
    int e = r * 256 + tid;
    int p = e >> 3, seg = e & 7;
    *(uint4*)(reads_bf + rowbase + (size_t)p * 1024 + seg * 8) =
        *(const uint4*)&in_s[p * 72 + seg * 8];
  }
}

// ----------------------------------------------------------------
extern "C" void kernel_launch(void* const* d_in, const int* in_sizes, int n_in,
                              void* d_out, int out_size, void* d_ws, size_t ws_size,
                              hipStream_t stream) {
  const float* out_f = (const float*)d_in[0];
  const float* Ww = (const float*)d_in[1];
  const float* Wr = (const float*)d_in[2];
  const float* decay = (const float*)d_in[3];
  const float* lalpha = (const float*)d_in[4];

  char* ws = (char*)d_ws;
  unsigned short* outbf = (unsigned short*)(ws + 0);
  unsigned short* vbf   = (unsigned short*)(ws + 33554432);
  unsigned short* wwbf  = (unsigned short*)(ws + 67108864);  // wrbf adjacent at +2MB
  unsigned short* wrbf  = (unsigned short*)(ws + 69206016);
  unsigned short* intra = (unsigned short*)(ws + 71303168);
  unsigned short* U     = (unsigned short*)(ws + 104857600);
  unsigned short* Wst   = (unsigned short*)(ws + 138412032);
  unsigned short* reads = (unsigned short*)(ws + 171966464);

  cast_all<<<dim3(9216), 256, 0, stream>>>(out_f, Ww, Wr, outbf, wwbf);

  // V = out @ W_write^T   (M=B*T=16384, N=D=1024, K=D=1024)
  gemm256<false><<<dim3(256), 512, 0, stream>>>(outbf, wwbf, nullptr, vbf, 16384, 1024, 1024);

  chunk_local<<<dim3(64, 64), 256, 0, stream>>>(outbf, vbf, decay, intra, U);

  scan_w<<<dim3(4, 64), 256, 0, stream>>>(U, decay, Wst);
  inter_combine<<<dim3(64, 64), 256, 0, stream>>>(outbf, Wst, intra, decay, lalpha, reads);

  // final = out + reads @ W_read^T (base added from bf16 copy)
  gemm256<true><<<dim3(256), 512, 0, stream>>>(reads, wrbf, outbf, d_out, 16384, 1024, 1024);
}

// Round 7
// 274.274 us; speedup vs baseline: 1.0093x; 1.0093x over previous
//
#include <hip/hip_runtime.h>
#include <hip/hip_bf16.h>
#include <stdint.h>

// Workspace layout (bytes):
//  outbf  [0,        33554432)   out cast to bf16        (B*T*D)
//  vbf    [33554432, 67108864)   V = out @ W_write^T, bf16
//  wwbf   [67108864, 69206016)   W_write bf16
//  wrbf   [69206016, 71303168)   W_read  bf16
//  intra  [71303168, 104857600)  intra reads bf16 (flat B,T,D layout)
//  U      [104857600,138412032)  per-chunk outer products bf16 [BH][64][64*64]
//  Wst    [138412032,171966464)  pre-chunk W states bf16 [BH][64][64*64]
//  reads  [171966464,205520896)  alpha*(inter+intra) bf16 (flat B,T,D)

typedef __bf16 bf16x8 __attribute__((ext_vector_type(8)));
typedef float f32x4 __attribute__((ext_vector_type(4)));

#define GAS __attribute__((address_space(1)))
#define LAS __attribute__((address_space(3)))

__device__ __forceinline__ unsigned short f2bf(float f) {
  unsigned u = __float_as_uint(f);
  u = (u + 0x7fffu + ((u >> 16) & 1u)) >> 16;   // RNE
  return (unsigned short)u;
}
__device__ __forceinline__ float bf2f(unsigned short h) {
  return __uint_as_float(((unsigned)h) << 16);
}

// ---------------------------------------------------------------- fused cast f32->bf16
__global__ __launch_bounds__(256) void cast_all(
    const float* __restrict__ outf, const float* __restrict__ w1,
    const float* __restrict__ w2, unsigned short* __restrict__ outbf,
    unsigned short* __restrict__ wbf) {
  int i = blockIdx.x * 256 + threadIdx.x;
  const float* src;
  uint4* dst;
  int j;
  if (i < 2097152) {
    src = outf; j = i; dst = (uint4*)outbf;
  } else {
    j = i - 2097152;
    dst = (uint4*)wbf;
    if (j < 131072) { src = w1; }
    else { src = w2; j -= 131072; dst += 131072; }
  }
  const float4* s = (const float4*)src + (size_t)j * 2;
  float4 f0 = s[0], f1 = s[1];
  union { uint4 u4; unsigned short us[8]; } o;
  o.us[0] = f2bf(f0.x); o.us[1] = f2bf(f0.y); o.us[2] = f2bf(f0.z); o.us[3] = f2bf(f0.w);
  o.us[4] = f2bf(f1.x); o.us[5] = f2bf(f1.y); o.us[6] = f2bf(f1.z); o.us[7] = f2bf(f1.w);
  dst[(i < 2097152) ? i : (i - 2097152 < 131072 ? i - 2097152 : i - 2097152 - 131072)] = o.u4;
}

// ---------------------------------------------------------------- 256x256 8-phase GEMM
// Frozen (R5): chunk-uniform XOR swizzle, bank-conflict-free (measured 0).
#define STG(XB, SLOT, HIDX, HF, KT)                                                  \
  do {                                                                               \
    if ((KT) < nT) {                                                                 \
      _Pragma("unroll") for (int r_ = 0; r_ < 2; r_++)                               \
          __builtin_amdgcn_global_load_lds(                                          \
              (GAS void*)(void*)((XB) +                                              \
                                 (size_t)((HF) * 128 + (tid >> 3) + r_ * 64) * K +   \
                                 ((KT) << 6) + srcc),                                \
              (LAS void*)(&lds[SLOT][HIDX][w64 * 512 + r_ * 4096]), 16, 0, 0);       \
    }                                                                                \
  } while (0)

#define DSRA(SLOT, MH)                                                               \
  _Pragma("unroll") for (int m_ = 0; m_ < 4; m_++)                                   \
  _Pragma("unroll") for (int ks_ = 0; ks_ < 2; ks_++)                                \
      a[m_][ks_] = *(const bf16x8*)&lds[SLOT][aH][((MH) * 64 + m_ * 16 + lm) * 64 +  \
                                                  (((ks_ * 4 + q4) ^ lsw) * 8)];

#define DSRB(SLOT, BB, N0)                                                           \
  _Pragma("unroll") for (int n_ = 0; n_ < 2; n_++)                                   \
  _Pragma("unroll") for (int ks_ = 0; ks_ < 2; ks_++)                                \
      BB[n_][ks_] = *(const bf16x8*)&lds[SLOT][bH][(brow0 + ((N0) + n_) * 16 + lm) * 64 + \
                                                   (((ks_ * 4 + q4) ^ lsw) * 8)];

#define MMA(MH, BB, N0)                                                              \
  __builtin_amdgcn_s_setprio(1);                                                     \
  _Pragma("unroll") for (int m_ = 0; m_ < 4; m_++)                                   \
  _Pragma("unroll") for (int n_ = 0; n_ < 2; n_++)                                   \
  _Pragma("unroll") for (int ks_ = 0; ks_ < 2; ks_++)                                \
      acc[(MH) * 4 + m_][(N0) + n_] = __builtin_amdgcn_mfma_f32_16x16x32_bf16(       \
          a[m_][ks_], BB[n_][ks_], acc[(MH) * 4 + m_][(N0) + n_], 0, 0, 0);          \
  __builtin_amdgcn_s_setprio(0);

#define BARW                                                                         \
  __builtin_amdgcn_s_barrier();                                                      \
  asm volatile("s_waitcnt lgkmcnt(0)" ::: "memory");                                 \
  __builtin_amdgcn_sched_barrier(0);

#define BARE                                                                         \
  __builtin_amdgcn_s_barrier();                                                      \
  __builtin_amdgcn_sched_barrier(0);

template <bool ADD>
__global__ __launch_bounds__(512, 2) void gemm256(
    const unsigned short* __restrict__ A, const unsigned short* __restrict__ B,
    const unsigned short* __restrict__ base_bf, void* __restrict__ Cout,
    int M, int N, int K) {
  __shared__ unsigned short lds[2][4][8192];
  int tid = threadIdx.x;
  int l = tid & 63, w64 = tid >> 6;
  int lm = l & 15, q4 = l >> 4;
  int lsw = lm & 7;
  int srcc = (((tid & 7) ^ ((tid >> 3) & 7)) * 8);
  int aH = w64 >> 2;
  int bH = 2 + ((w64 & 3) >> 1);
  int brow0 = (w64 & 1) * 64;
  int id = blockIdx.x;
  int xcd = id & 7, s = id >> 3;
  int bn = s & 3, bm = (s >> 2) * 8 + xcd;
  const unsigned short* Ab = A + (size_t)bm * 256 * K;
  const unsigned short* Bb = B + (size_t)bn * 256 * K;
  const int nT = K >> 6, nI = nT >> 1;

  STG(Bb, 0, 2, 0, 0); STG(Bb, 0, 3, 1, 0);
  STG(Ab, 0, 0, 0, 0); STG(Ab, 0, 1, 1, 0);
  STG(Bb, 1, 2, 0, 1); STG(Bb, 1, 3, 1, 1);
  asm volatile("s_waitcnt vmcnt(4)" ::: "memory");
  __builtin_amdgcn_s_barrier();
  __builtin_amdgcn_sched_barrier(0);

  f32x4 acc[8][4];
  if constexpr (ADD) {
#pragma unroll
    for (int mh = 0; mh < 2; mh++)
#pragma unroll
      for (int m = 0; m < 4; m++)
#pragma unroll
        for (int nf = 0; nf < 4; nf++) {
          int r0 = bm * 256 + (w64 >> 2) * 128 + mh * 64 + m * 16 + q4 * 4;
          int col = bn * 256 + (w64 & 3) * 64 + nf * 16 + lm;
#pragma unroll
          for (int j = 0; j < 4; j++)
            acc[mh * 4 + m][nf][j] = bf2f(base_bf[(size_t)(r0 + j) * N + col]);
        }
  } else {
#pragma unroll
    for (int mf = 0; mf < 8; mf++)
#pragma unroll
      for (int nf = 0; nf < 4; nf++) acc[mf][nf] = (f32x4){0.f, 0.f, 0.f, 0.f};
  }

  bf16x8 a[4][2], b0[2][2], b1[2][2];
  for (int i = 0; i < nI; i++) {
    int t1 = 2 * i + 1, t2 = 2 * i + 2, t3 = 2 * i + 3;
    DSRA(0, 0); DSRB(0, b0, 0); STG(Ab, 1, 0, 0, t1);   // P1
    BARW; MMA(0, b0, 0); BARE;
    DSRB(0, b1, 2); STG(Ab, 1, 1, 1, t1);               // P2
    BARW; MMA(0, b1, 2); BARE;
    DSRA(0, 1); STG(Bb, 0, 2, 0, t2);                   // P3
    BARW; MMA(1, b1, 2); BARE;
    STG(Bb, 0, 3, 1, t2);                               // P4
    BARW; MMA(1, b0, 0);
    if (i < nI - 1) { asm volatile("s_waitcnt vmcnt(4)" ::: "memory"); }
    else            { asm volatile("s_waitcnt vmcnt(0)" ::: "memory"); }
    BARE;
    DSRA(1, 0); DSRB(1, b0, 0); STG(Ab, 0, 0, 0, t2);   // P5
    BARW; MMA(0, b0, 0); BARE;
    DSRB(1, b1, 2); STG(Ab, 0, 1, 1, t2);               // P6
    BARW; MMA(0, b1, 2); BARE;
    DSRA(1, 1); STG(Bb, 1, 2, 0, t3);                   // P7
    BARW; MMA(1, b1, 2); BARE;
    STG(Bb, 1, 3, 1, t3);                               // P8
    BARW; MMA(1, b0, 0);
    if (i < nI - 1) { asm volatile("s_waitcnt vmcnt(4)" ::: "memory"); }
    BARE;
  }

#pragma unroll
  for (int mh = 0; mh < 2; mh++)
#pragma unroll
    for (int m = 0; m < 4; m++)
#pragma unroll
      for (int nf = 0; nf < 4; nf++) {
        int r0 = bm * 256 + (w64 >> 2) * 128 + mh * 64 + m * 16 + q4 * 4;
        int col = bn * 256 + (w64 & 3) * 64 + nf * 16 + lm;
#pragma unroll
        for (int j = 0; j < 4; j++) {
          if constexpr (ADD)
            ((float*)Cout)[(size_t)(r0 + j) * N + col] = acc[mh * 4 + m][nf][j];
          else
            ((unsigned short*)Cout)[(size_t)(r0 + j) * N + col] = f2bf(acc[mh * 4 + m][nf][j]);
        }
      }
}

// ---------------------------------------------------------------- per-chunk local work
// R7: transposed arrays (vT_s, wkT_s) stored with bijective group-XOR relayout:
// element (row d, token p) lives at column ((p>>3)^((d>>3)&7))*8 + (p&7).
// Staging writes go from ~16-way to 2-way bank conflict (seg enters low addr bits);
// reads fetch logical group g at physical group g^((row>>3)&7) — correct tokens in
// order, so MFMA pairing and pw_s indexing are unchanged. Bit-identical values.
__global__ __launch_bounds__(256) void chunk_local(
    const unsigned short* __restrict__ rkg,   // outbf flat [B*T*D]
    const unsigned short* __restrict__ vg,    // vbf flat
    const float* __restrict__ decay,
    unsigned short* __restrict__ intra_bf,    // flat [B*T*D]
    unsigned short* __restrict__ U_bf) {      // [BH][64][64*64]
  int c = blockIdx.x, bh = blockIdx.y;
  int b = bh >> 4, h = bh & 15;
  int tid = threadIdx.x, l = tid & 63, w = tid >> 6;
  float gamma = 1.0f / (1.0f + __expf(-decay[h]));
  float lg = __logf(gamma);

  __shared__ unsigned short kr_s[65 * 72];   // kr_s[p] = token c*64-1+p (p=0..64)
  __shared__ unsigned short wkT_s[64 * 72];  // transpose of kr_s rows 0..63 (swizzled)
  __shared__ unsigned short vT_s[64 * 72];   // transpose of v (swizzled)
  __shared__ unsigned short S_s[64 * 72];
  __shared__ float pw_s[64];                 // gamma^d

  if (tid < 64) pw_s[tid] = __expf(lg * (float)tid);

  const size_t rowbase = (((size_t)b * 4096 + (size_t)c * 64) * 1024) + h * 64;
  const size_t bb = (size_t)b * 4096;

#pragma unroll
  for (int r = 0; r < 2; r++) {
    int e = r * 256 + tid;
    int p = e >> 3, seg = e & 7;
    int pc = (((p >> 3) ^ seg) << 3) | (p & 7);   // swizzled column for rows d: d>>3==seg
    uint4 dv = *(const uint4*)(vg + rowbase + (size_t)p * 1024 + seg * 8);
    {
      unsigned uu[4] = {dv.x, dv.y, dv.z, dv.w};
#pragma unroll
      for (int qq = 0; qq < 4; qq++) {
        vT_s[(seg * 8 + qq * 2) * 72 + pc] = (unsigned short)(uu[qq] & 0xffffu);
        vT_s[(seg * 8 + qq * 2 + 1) * 72 + pc] = (unsigned short)(uu[qq] >> 16);
      }
    }
    int tg = c * 64 - 1 + p;
    uint4 dw = make_uint4(0u, 0u, 0u, 0u);
    if (tg >= 0) dw = *(const uint4*)(rkg + (bb + tg) * 1024 + h * 64 + seg * 8);
    *(uint4*)&kr_s[p * 72 + seg * 8] = dw;
    {
      unsigned uu[4] = {dw.x, dw.y, dw.z, dw.w};
#pragma unroll
      for (int qq = 0; qq < 4; qq++) {
        wkT_s[(seg * 8 + qq * 2) * 72 + pc] = (unsigned short)(uu[qq] & 0xffffu);
        wkT_s[(seg * 8 + qq * 2 + 1) * 72 + pc] = (unsigned short)(uu[qq] >> 16);
      }
    }
  }
  if (tid < 8) {
    uint4 dw = *(const uint4*)(rkg + (bb + (size_t)c * 64 + 63) * 1024 + h * 64 + tid * 8);
    *(uint4*)&kr_s[64 * 72 + tid * 8] = dw;
  }
  __syncthreads();

  int lm = l & 15, q4 = l >> 4;
  int lh = lm >> 3;                       // high bit of lm -> (row>>3) parity

  // Phase 1: S = rk @ wk^T, mask, bf16  (kr_s unswizzled)
  {
    bf16x8 a0 = *(const bf16x8*)&kr_s[(w * 16 + lm + 1) * 72 + q4 * 8];
    bf16x8 a1 = *(const bf16x8*)&kr_s[(w * 16 + lm + 1) * 72 + 32 + q4 * 8];
#pragma unroll
    for (int ni = 0; ni < 4; ni++) {
      bf16x8 b0 = *(const bf16x8*)&kr_s[(ni * 16 + lm) * 72 + q4 * 8];
      bf16x8 b1 = *(const bf16x8*)&kr_s[(ni * 16 + lm) * 72 + 32 + q4 * 8];
      f32x4 acc = {0.f, 0.f, 0.f, 0.f};
      acc = __builtin_amdgcn_mfma_f32_16x16x32_bf16(a0, b0, acc, 0, 0, 0);
      acc = __builtin_amdgcn_mfma_f32_16x16x32_bf16(a1, b1, acc, 0, 0, 0);
#pragma unroll
      for (int j = 0; j < 4; j++) {
        int p = w * 16 + q4 * 4 + j;
        int q = ni * 16 + lm;
        float m = (p > q) ? pw_s[p - 1 - q] : 0.0f;
        S_s[p * 72 + q] = f2bf(acc[j] * m);
      }
    }
  }
  __syncthreads();

  // Phase 2: intra = (S.M) @ v  -> bounce result through S_s, coalesced store
  {
    bf16x8 a0 = *(const bf16x8*)&S_s[(w * 16 + lm) * 72 + q4 * 8];
    bf16x8 a1 = *(const bf16x8*)&S_s[(w * 16 + lm) * 72 + 32 + q4 * 8];
    f32x4 accs[4];
#pragma unroll
    for (int ni = 0; ni < 4; ni++) {
      int kk = (ni * 2 + lh) & 7;         // (row>>3)&7 for rows ni*16+lm
      bf16x8 b0 = *(const bf16x8*)&vT_s[(ni * 16 + lm) * 72 + ((q4 ^ kk) << 3)];
      bf16x8 b1 = *(const bf16x8*)&vT_s[(ni * 16 + lm) * 72 + (((4 + q4) ^ kk) << 3)];
      f32x4 acc = {0.f, 0.f, 0.f, 0.f};
      acc = __builtin_amdgcn_mfma_f32_16x16x32_bf16(a0, b0, acc, 0, 0, 0);
      accs[ni] = __builtin_amdgcn_mfma_f32_16x16x32_bf16(a1, b1, acc, 0, 0, 0);
    }
    __syncthreads();   // all S_s fragment reads complete
#pragma unroll
    for (int ni = 0; ni < 4; ni++)
#pragma unroll
      for (int j = 0; j < 4; j++) {
        int p = w * 16 + q4 * 4 + j;
        int i = ni * 16 + lm;
        S_s[p * 72 + i] = f2bf(accs[ni][j]);
      }
    __syncthreads();
#pragma unroll
    for (int r = 0; r < 2; r++) {
      int e = r * 256 + tid;
      int p = e >> 3, seg = e & 7;
      *(uint4*)(intra_bf + rowbase + (size_t)p * 1024 + seg * 8) =
          *(const uint4*)&S_s[p * 72 + seg * 8];
    }
  }

  // Phase 3: U = (v * g_w)^T @ wk  -> bounce result through wkT_s, coalesced store
  {
    int kA = (w * 2 + lh) & 7;            // (row>>3)&7 for rows w*16+lm
    bf16x8 a0 = *(const bf16x8*)&vT_s[(w * 16 + lm) * 72 + ((q4 ^ kA) << 3)];
    bf16x8 a1 = *(const bf16x8*)&vT_s[(w * 16 + lm) * 72 + (((4 + q4) ^ kA) << 3)];
#pragma unroll
    for (int jj = 0; jj < 8; jj++) {
      int p0 = q4 * 8 + jj;               // logical token indices unchanged by relayout
      a0[jj] = (__bf16)((float)a0[jj] * pw_s[63 - p0]);
      a1[jj] = (__bf16)((float)a1[jj] * pw_s[63 - (p0 + 32)]);
    }
    f32x4 accs[4];
#pragma unroll
    for (int nj = 0; nj < 4; nj++) {
      int kB = (nj * 2 + lh) & 7;
      bf16x8 b0 = *(const bf16x8*)&wkT_s[(nj * 16 + lm) * 72 + ((q4 ^ kB) << 3)];
      bf16x8 b1 = *(const bf16x8*)&wkT_s[(nj * 16 + lm) * 72 + (((4 + q4) ^ kB) << 3)];
      f32x4 acc = {0.f, 0.f, 0.f, 0.f};
      acc = __builtin_amdgcn_mfma_f32_16x16x32_bf16(a0, b0, acc, 0, 0, 0);
      accs[nj] = __builtin_amdgcn_mfma_f32_16x16x32_bf16(a1, b1, acc, 0, 0, 0);
    }
    __syncthreads();   // all wkT_s fragment reads complete
#pragma unroll
    for (int nj = 0; nj < 4; nj++)
#pragma unroll
      for (int j = 0; j < 4; j++) {
        int i = w * 16 + q4 * 4 + j;
        int col = nj * 16 + lm;
        wkT_s[i * 72 + col] = f2bf(accs[nj][j]);   // plain layout; full overwrite
      }
    __syncthreads();
    size_t ub = ((size_t)bh * 64 + c) * 4096;
#pragma unroll
    for (int r = 0; r < 2; r++) {
      int e = r * 256 + tid;
      *(uint4*)(U_bf + ub + (size_t)e * 8) = *(const uint4*)&wkT_s[(e >> 3) * 72 + (e & 7) * 8];
    }
  }
}

// ---------------------------------------------------------------- parallel weighted prefix scan
__global__ __launch_bounds__(256) void scan_w(
    const unsigned short* __restrict__ U_bf, const float* __restrict__ decay,
    unsigned short* __restrict__ Wst) {
  int nsl = blockIdx.x, bh = blockIdx.y;
  int h = bh & 15;
  float gamma = 1.0f / (1.0f + __expf(-decay[h]));
  float gC = __expf(64.0f * __logf(gamma));
  int n0 = nsl * 1024 + threadIdx.x * 4;
  const unsigned short* Ub = U_bf + (size_t)bh * 64 * 4096 + n0;
  unsigned short* Wb = Wst + (size_t)bh * 64 * 4096 + n0;
  float w0 = 0.f, w1 = 0.f, w2 = 0.f, w3 = 0.f;
#pragma unroll
  for (int c = 0; c < 64; c++) {
    uint2 u = *(const uint2*)(Ub + (size_t)c * 4096);
    ushort4 sv;
    sv.x = f2bf(w0); sv.y = f2bf(w1); sv.z = f2bf(w2); sv.w = f2bf(w3);
    *(ushort4*)(Wb + (size_t)c * 4096) = sv;
    w0 = gC * w0 + bf2f((unsigned short)(u.x & 0xffffu));
    w1 = gC * w1 + bf2f((unsigned short)(u.x >> 16));
    w2 = gC * w2 + bf2f((unsigned short)(u.y & 0xffffu));
    w3 = gC * w3 + bf2f((unsigned short)(u.y >> 16));
  }
}

// ---------------------------------------------------------------- inter + combine (parallel)
__global__ __launch_bounds__(256) void inter_combine(
    const unsigned short* __restrict__ rkg, const unsigned short* __restrict__ Wst,
    const unsigned short* __restrict__ intra_bf,
    const float* __restrict__ decay, const float* __restrict__ log_alpha,
    unsigned short* __restrict__ reads_bf) {
  int c = blockIdx.x, bh = blockIdx.y;
  int b = bh >> 4, h = bh & 15;
  int tid = threadIdx.x, l = tid & 63, w = tid >> 6;
  int lm = l & 15, q4 = l >> 4;
  float gamma = 1.0f / (1.0f + __expf(-decay[h]));
  float lg = __logf(gamma);
  float alpha = __expf(log_alpha[h]);

  __shared__ unsigned short rk_s[64 * 72];
  __shared__ unsigned short W_s[64 * 72];
  __shared__ unsigned short in_s[64 * 72];
  __shared__ float pw_s[64];

  if (tid < 64) pw_s[tid] = __expf(lg * (float)tid);

  const size_t rowbase = (((size_t)b * 4096 + (size_t)c * 64) * 1024) + h * 64;
  const size_t wbase = ((size_t)bh * 64 + c) * 4096;

#pragma unroll
  for (int r = 0; r < 2; r++) {
    int e = r * 256 + tid;
    int p = e >> 3, seg = (e & 7) * 8;
    *(uint4*)&rk_s[p * 72 + seg] = *(const uint4*)(rkg + rowbase + (size_t)p * 1024 + seg);
    *(uint4*)&in_s[p * 72 + seg] = *(const uint4*)(intra_bf + rowbase + (size_t)p * 1024 + seg);
    *(uint4*)&W_s[p * 72 + seg] = *(const uint4*)(Wst + wbase + (size_t)p * 64 + seg);
  }
  __syncthreads();

  bf16x8 a0 = *(const bf16x8*)&rk_s[(w * 16 + lm) * 72 + q4 * 8];
  bf16x8 a1 = *(const bf16x8*)&rk_s[(w * 16 + lm) * 72 + 32 + q4 * 8];
#pragma unroll
  for (int ni = 0; ni < 4; ni++) {
    bf16x8 b0 = *(const bf16x8*)&W_s[(ni * 16 + lm) * 72 + q4 * 8];
    bf16x8 b1 = *(const bf16x8*)&W_s[(ni * 16 + lm) * 72 + 32 + q4 * 8];
    f32x4 acc = {0.f, 0.f, 0.f, 0.f};
    acc = __builtin_amdgcn_mfma_f32_16x16x32_bf16(a0, b0, acc, 0, 0, 0);
    acc = __builtin_amdgcn_mfma_f32_16x16x32_bf16(a1, b1, acc, 0, 0, 0);
#pragma unroll
    for (int j = 0; j < 4; j++) {
      int p = w * 16 + q4 * 4 + j;
      int i = ni * 16 + lm;
      in_s[p * 72 + i] = f2bf(alpha * (acc[j] * pw_s[p] + bf2f(in_s[p * 72 + i])));
    }
  }
  __syncthreads();
#pragma unroll
  for (int r = 0; r < 2; r++) {
    int e = r * 256 + tid;
    int p = e >> 3, seg = e & 7;
    *(uint4*)(reads_bf + rowbase + (size_t)p * 1024 + seg * 8) =
        *(const uint4*)&in_s[p * 72 + seg * 8];
  }
}

// ----------------------------------------------------------------
extern "C" void kernel_launch(void* const* d_in, const int* in_sizes, int n_in,
                              void* d_out, int out_size, void* d_ws, size_t ws_size,
                              hipStream_t stream) {
  const float* out_f = (const float*)d_in[0];
  const float* Ww = (const float*)d_in[1];
  const float* Wr = (const float*)d_in[2];
  const float* decay = (const float*)d_in[3];
  const float* lalpha = (const float*)d_in[4];

  char* ws = (char*)d_ws;
  unsigned short* outbf = (unsigned short*)(ws + 0);
  unsigned short* vbf   = (unsigned short*)(ws + 33554432);
  unsigned short* wwbf  = (unsigned short*)(ws + 67108864);  // wrbf adjacent at +2MB
  unsigned short* wrbf  = (unsigned short*)(ws + 69206016);
  unsigned short* intra = (unsigned short*)(ws + 71303168);
  unsigned short* U     = (unsigned short*)(ws + 104857600);
  unsigned short* Wst   = (unsigned short*)(ws + 138412032);
  unsigned short* reads = (unsigned short*)(ws + 171966464);

  cast_all<<<dim3(9216), 256, 0, stream>>>(out_f, Ww, Wr, outbf, wwbf);

  // V = out @ W_write^T   (M=B*T=16384, N=D=1024, K=D=1024)
  gemm256<false><<<dim3(256), 512, 0, stream>>>(outbf, wwbf, nullptr, vbf, 16384, 1024, 1024);

  chunk_local<<<dim3(64, 64), 256, 0, stream>>>(outbf, vbf, decay, intra, U);

  scan_w<<<dim3(4, 64), 256, 0, stream>>>(U, decay, Wst);
  inter_combine<<<dim3(64, 64), 256, 0, stream>>>(outbf, Wst, intra, decay, lalpha, reads);

  // final = out + reads @ W_read^T (base added from bf16 copy)
  gemm256<true><<<dim3(256), 512, 0, stream>>>(reads, wrbf, outbf, d_out, 16384, 1024, 1024);
}